// Round 12
// baseline (236.653 us; speedup 1.0000x reference)
//
#include <hip/hip_runtime.h>

// Problem constants (from reference)
#define NB 64      // B
#define NC 23      // C
#define NL 26000   // L
#define ND 64      // D
#define NE 512     // E
#define NK 3       // K
#define FP4  (NL * NK / 4)          // 19500 float4 per (b,c) slice
#define CFP4 (NC * FP4)             // 448500 float4 per b slice
#define CHUNK 3504                  // float4 per block chunk (56 KB)
#define NCHUNK 128                  // 128 * 3504 = 448512 >= 448500
#define NJ 14                       // ceil(CHUNK / 256)
#define GB 8                        // b's per block (grid.y = 8)

typedef float v4f __attribute__((ext_vector_type(4)));

// ---------------------------------------------------------------------------
// Kernel 1: e[b,c,k]  (proven, ~6 us)
// ---------------------------------------------------------------------------
__global__ __launch_bounds__(256) void eos_e_kernel(
    const float* __restrict__ eos_emb,  // [B][C][E]
    const float* __restrict__ eos_W,    // [D][E]
    const float* __restrict__ eos_b,    // [D]
    const float* __restrict__ fc_W,     // [K][2D]
    const float* __restrict__ fc_b,     // [K]
    float* __restrict__ e_out)          // [B*C][K]
{
    const int bc = blockIdx.x;
    const int t  = threadIdx.x;
    const int q  = t & 3;
    const int d  = t >> 2;

    __shared__ v4f xs4[NE / 4];
    if (t < NE / 4)
        xs4[t] = reinterpret_cast<const v4f*>(eos_emb + (size_t)bc * NE)[t];
    __syncthreads();

    const v4f* wrow = reinterpret_cast<const v4f*>(eos_W + (size_t)d * NE);
    v4f acc = (v4f)(0.f);
    #pragma unroll 8
    for (int j = 0; j < NE / 16; ++j) {
        const int idx = q + 4 * j;
        acc += wrow[idx] * xs4[idx];
    }
    float p = (acc.x + acc.y) + (acc.z + acc.w);
    p += __shfl_xor(p, 1, 64);
    p += __shfl_xor(p, 2, 64);
    const float eosd = p + eos_b[d];

    __shared__ float part[4][NK];
    #pragma unroll
    for (int k = 0; k < NK; ++k) {
        float pk = eosd * fc_W[k * (2 * ND) + ND + d];   // We[k][d]
        pk += __shfl_xor(pk,  4, 64);
        pk += __shfl_xor(pk,  8, 64);
        pk += __shfl_xor(pk, 16, 64);
        pk += __shfl_xor(pk, 32, 64);
        if ((t & 63) == 0) part[t >> 6][k] = pk;
    }
    __syncthreads();
    if (t < NK)
        e_out[(size_t)bc * NK + t] =
            part[0][t] + part[1][t] + part[2][t] + part[3][t] + fc_b[t];
}

// ---------------------------------------------------------------------------
// Kernel A: a[c,l,k] -> workspace (proven quad-coop gather)
// ---------------------------------------------------------------------------
__global__ __launch_bounds__(256) void a_kernel(
    const int*   __restrict__ bin_ids,    // [C][L]
    const float* __restrict__ emb_table,  // [V][D]
    const float* __restrict__ fc_W,       // [K][2D]
    float* __restrict__ a_out)            // [C][L][K]
{
    const int c = blockIdx.y;
    const int t = threadIdx.x;
    const int q = t & 3;
    const int r = t >> 2;
    const int l = blockIdx.x * 64 + r;

    __shared__ v4f wb4[NK][ND / 4];
    if (t < NK * (ND / 4)) {
        const int k = t / (ND / 4), i = t % (ND / 4);
        wb4[k][i] = reinterpret_cast<const v4f*>(fc_W + (size_t)k * (2 * ND))[i];
    }
    __syncthreads();
    if (l >= NL) return;

    const int row = bin_ids[(size_t)c * NL + l];
    const v4f* er = reinterpret_cast<const v4f*>(emb_table + (size_t)row * ND);

    v4f s0 = (v4f)(0.f), s1 = (v4f)(0.f), s2 = (v4f)(0.f);
    #pragma unroll
    for (int j = 0; j < 4; ++j) {
        const int idx = q + 4 * j;
        const v4f v = er[idx];
        s0 += v * wb4[0][idx];
        s1 += v * wb4[1][idx];
        s2 += v * wb4[2][idx];
    }
    float a0 = (s0.x + s0.y) + (s0.z + s0.w);
    float a1 = (s1.x + s1.y) + (s1.z + s1.w);
    float a2 = (s2.x + s2.y) + (s2.z + s2.w);
    a0 += __shfl_xor(a0, 1, 64); a0 += __shfl_xor(a0, 2, 64);
    a1 += __shfl_xor(a1, 1, 64); a1 += __shfl_xor(a1, 2, 64);
    a2 += __shfl_xor(a2, 1, 64); a2 += __shfl_xor(a2, 2, 64);

    if (q < NK) {
        const float val = (q == 0) ? a0 : (q == 1) ? a1 : a2;
        a_out[((size_t)c * NL + l) * NK + q] = val;
    }
}

// ---------------------------------------------------------------------------
// Kernel B: R7 flattened b-stream store (the 146.6 us record holder).
// ---------------------------------------------------------------------------
__global__ __launch_bounds__(256) void bstream_kernel(
    const float* __restrict__ a_in,   // [CFP4] float4
    const float* __restrict__ e_in,   // [B*C][K]
    float* __restrict__ out)          // [B][CFP4] float4
{
    const int bx = blockIdx.x;        // chunk 0..127
    const int b0 = blockIdx.y * GB;   // b-group start
    const int t  = threadIdx.x;

    __shared__ v4f e4[3][NC][GB];
    for (int i = t; i < 3 * NC * GB; i += 256) {
        const int p   = i / (NC * GB);
        const int rem = i - p * (NC * GB);
        const int c   = rem / GB;
        const int bl  = rem - c * GB;
        const float* ep = e_in + ((size_t)(b0 + bl) * NC + c) * NK;
        const float e0 = ep[0], e1 = ep[1], e2 = ep[2];
        v4f v;
        if      (p == 0) { v.x = e0; v.y = e1; v.z = e2; v.w = e0; }
        else if (p == 1) { v.x = e1; v.y = e2; v.z = e0; v.w = e1; }
        else             { v.x = e2; v.y = e0; v.z = e1; v.w = e2; }
        e4[p][c][bl] = v;
    }
    __syncthreads();

    const int base = bx * CHUNK;
    const v4f* a4 = reinterpret_cast<const v4f*>(a_in);

    v4f        av[NJ];
    const v4f* eptr[NJ];
    bool       gj[NJ];
    #pragma unroll
    for (int j = 0; j < NJ; ++j) {
        const int fo = j * 256 + t;
        const int f  = base + fo;
        gj[j] = (fo < CHUNK) && (f < CFP4);
        const int fc = gj[j] ? f : 0;
        eptr[j] = &e4[fc % 3][fc / FP4][0];
        av[j]   = gj[j] ? a4[fc] : (v4f)(0.f);
    }

    v4f* o4 = reinterpret_cast<v4f*>(out);
    size_t obase = (size_t)b0 * CFP4 + base;
    #pragma unroll 2
    for (int bl = 0; bl < GB; ++bl) {
        #pragma unroll
        for (int j = 0; j < NJ; ++j) {
            if (gj[j]) {
                const v4f ev = eptr[j][bl];
                v4f o;
                o.x = fmaxf(av[j].x + ev.x, 0.f);
                o.y = fmaxf(av[j].y + ev.y, 0.f);
                o.z = fmaxf(av[j].z + ev.z, 0.f);
                o.w = fmaxf(av[j].w + ev.w, 0.f);
                o4[obase + j * 256 + t] = o;
            }
        }
        obase += CFP4;
    }
}

// ---------------------------------------------------------------------------
// Fused fallback for the case ws_size is too small.
// ---------------------------------------------------------------------------
__global__ __launch_bounds__(256) void decoder_fused_kernel(
    const int*   __restrict__ bin_ids,
    const float* __restrict__ emb_table,
    const float* __restrict__ fc_W,
    const float* __restrict__ e_in,
    float* __restrict__ out)
{
    const int c   = blockIdx.y;
    const int tid = threadIdx.x;
    const int l   = blockIdx.x * 256 + tid;

    __shared__ float wb[NK][ND];
    __shared__ float es[NB * NK];

    if (tid < NK * ND)
        wb[tid / ND][tid % ND] = fc_W[(tid / ND) * (2 * ND) + (tid % ND)];
    if (tid < NB * NK) {
        int b = tid / NK, k = tid % NK;
        es[tid] = e_in[((size_t)b * NC + c) * NK + k];
    }
    __syncthreads();
    if (l >= NL) return;

    const int row = bin_ids[(size_t)c * NL + l];
    const float4* er = reinterpret_cast<const float4*>(emb_table + (size_t)row * ND);
    const float4* w0 = reinterpret_cast<const float4*>(wb[0]);
    const float4* w1 = reinterpret_cast<const float4*>(wb[1]);
    const float4* w2 = reinterpret_cast<const float4*>(wb[2]);

    float a0 = 0.f, a1 = 0.f, a2 = 0.f;
    #pragma unroll
    for (int i = 0; i < ND / 4; ++i) {
        float4 v  = er[i];
        float4 p0 = w0[i], p1 = w1[i], p2 = w2[i];
        a0 += v.x * p0.x + v.y * p0.y + v.z * p0.z + v.w * p0.w;
        a1 += v.x * p1.x + v.y * p1.y + v.z * p1.z + v.w * p1.w;
        a2 += v.x * p2.x + v.y * p2.y + v.z * p2.z + v.w * p2.w;
    }

    size_t obase = ((size_t)c * NL + l) * NK;
    const size_t bstride = (size_t)NC * NL * NK;
    #pragma unroll 4
    for (int b = 0; b < NB; ++b) {
        const float e0 = es[b * NK + 0];
        const float e1 = es[b * NK + 1];
        const float e2 = es[b * NK + 2];
        out[obase + 0] = fmaxf(a0 + e0, 0.f);
        out[obase + 1] = fmaxf(a1 + e1, 0.f);
        out[obase + 2] = fmaxf(a2 + e2, 0.f);
        obase += bstride;
    }
}

extern "C" void kernel_launch(void* const* d_in, const int* in_sizes, int n_in,
                              void* d_out, int out_size, void* d_ws, size_t ws_size,
                              hipStream_t stream) {
    const float* eos_emb   = (const float*)d_in[0];
    const int*   bin_ids   = (const int*)  d_in[1];
    const float* emb_table = (const float*)d_in[2];
    const float* eos_W     = (const float*)d_in[3];
    const float* eos_b     = (const float*)d_in[4];
    const float* fc_W      = (const float*)d_in[5];
    const float* fc_b      = (const float*)d_in[6];
    float*       out       = (float*)d_out;

    // ws layout: [0,32KB) e ; [32KB, ~7.2MB+32KB) a ; [16MB, 16MB+460MB) dummy
    float*  e_ws = (float*)d_ws;
    const size_t a_off_bytes = 32768;
    float*  a_ws = (float*)((char*)d_ws + a_off_bytes);
    const size_t a_bytes = (size_t)NC * NL * NK * sizeof(float);

    const size_t dummy_off = 16ull * 1024 * 1024;
    const size_t out_bytes = (size_t)NB * CFP4 * 16;   // 459.3 MB
    float* dummy = (float*)((char*)d_ws + dummy_off);

    eos_e_kernel<<<NB * NC, 256, 0, stream>>>(eos_emb, eos_W, eos_b, fc_W, fc_b, e_ws);

    if (ws_size >= a_off_bytes + a_bytes) {
        dim3 grid_a((NL + 63) / 64, NC);            // 9361 blocks
        a_kernel<<<grid_a, 256, 0, stream>>>(bin_ids, emb_table, fc_W, a_ws);

        dim3 grid_b(NCHUNK, NB / GB);               // 128 x 8 = 1024 blocks
        bstream_kernel<<<grid_b, 256, 0, stream>>>(a_ws, e_ws, out);

        // MEASUREMENT: identical second store pass into ws scratch.
        // dur_us - ~150 = T_store of one pass.
        if (ws_size >= dummy_off + out_bytes) {
            bstream_kernel<<<grid_b, 256, 0, stream>>>(a_ws, e_ws, dummy);
        }
    } else {
        dim3 grid((NL + 255) / 256, NC);
        decoder_fused_kernel<<<grid, 256, 0, stream>>>(bin_ids, emb_table, fc_W, e_ws, out);
    }
}

// Round 13
// 172.683 us; speedup vs baseline: 1.3704x; 1.3704x over previous
//
#include <hip/hip_runtime.h>

// Problem constants (from reference)
#define NB 64      // B
#define NC 23      // C
#define NL 26000   // L
#define ND 64      // D
#define NE 512     // E
#define NK 3       // K
#define FP4  (NL * NK / 4)          // 19500 float4 per (b,c) slice
#define CFP4 (NC * FP4)             // 448500 float4 per b slice
#define CHUNK 3504                  // float4 per block chunk (56 KB)
#define NCHUNK 128                  // 128 * 3504 = 448512 >= 448500
#define NJ 14                       // ceil(CHUNK / 256)
#define GB 8                        // b's per block (grid.y = 8)
#define NBC (NB * NC)               // 1472 eos units
#define ABLK 407                    // a-blocks per c (407*64 = 26048 >= 26000)
#define ATOT (ABLK * NC)            // 9361 a-blocks

typedef float v4f __attribute__((ext_vector_type(4)));

// ---------------------------------------------------------------------------
// Merged prep kernel: blocks [0, NBC) compute e[b,c,:]; blocks [NBC, NBC+ATOT)
// compute a[c,l,:].  One launch: kills one inter-kernel drain and overlaps
// eos's L2-bound reads under a's HBM streaming.
// ---------------------------------------------------------------------------
__global__ __launch_bounds__(256) void prep_kernel(
    const float* __restrict__ eos_emb,   // [B][C][E]
    const int*   __restrict__ bin_ids,   // [C*L]
    const float* __restrict__ emb_table, // [V][D]
    const float* __restrict__ eos_W,     // [D][E]
    const float* __restrict__ eos_b,     // [D]
    const float* __restrict__ fc_W,      // [K][2D]
    const float* __restrict__ fc_b,      // [K]
    float* __restrict__ e_out,           // [B*C][K]
    float* __restrict__ a_out)           // [C][L][K]
{
    const int bx = blockIdx.x;
    const int t  = threadIdx.x;
    const int q  = t & 3;

    __shared__ v4f   xs4[NE / 4];        // eos path (2 KB)
    __shared__ float part[4][NK];
    __shared__ v4f   wb4[NK][ND / 4];    // a path (768 B)

    if (bx < NBC) {
        // ---------------- eos path ----------------
        const int bc = bx;
        const int d  = t >> 2;

        if (t < NE / 4)
            xs4[t] = reinterpret_cast<const v4f*>(eos_emb + (size_t)bc * NE)[t];
        __syncthreads();

        const v4f* wrow = reinterpret_cast<const v4f*>(eos_W + (size_t)d * NE);
        v4f acc = (v4f)(0.f);
        #pragma unroll 8
        for (int j = 0; j < NE / 16; ++j) {
            const int idx = q + 4 * j;
            acc += wrow[idx] * xs4[idx];
        }
        float p = (acc.x + acc.y) + (acc.z + acc.w);
        p += __shfl_xor(p, 1, 64);
        p += __shfl_xor(p, 2, 64);
        const float eosd = p + eos_b[d];

        #pragma unroll
        for (int k = 0; k < NK; ++k) {
            float pk = eosd * fc_W[k * (2 * ND) + ND + d];   // We[k][d]
            pk += __shfl_xor(pk,  4, 64);
            pk += __shfl_xor(pk,  8, 64);
            pk += __shfl_xor(pk, 16, 64);
            pk += __shfl_xor(pk, 32, 64);
            if ((t & 63) == 0) part[t >> 6][k] = pk;
        }
        __syncthreads();
        if (t < NK)
            e_out[(size_t)bc * NK + t] =
                part[0][t] + part[1][t] + part[2][t] + part[3][t] + fc_b[t];
    } else {
        // ---------------- a path ----------------
        const int ab = bx - NBC;        // 0..ATOT-1
        const int c  = ab / ABLK;
        const int lb = ab - c * ABLK;
        const int r  = t >> 2;
        const int l  = lb * 64 + r;

        if (t < NK * (ND / 4)) {
            const int k = t / (ND / 4), i = t % (ND / 4);
            wb4[k][i] = reinterpret_cast<const v4f*>(fc_W + (size_t)k * (2 * ND))[i];
        }
        __syncthreads();
        if (l >= NL) return;

        const int row = bin_ids[(size_t)c * NL + l];
        const v4f* er = reinterpret_cast<const v4f*>(emb_table + (size_t)row * ND);

        v4f s0 = (v4f)(0.f), s1 = (v4f)(0.f), s2 = (v4f)(0.f);
        #pragma unroll
        for (int j = 0; j < 4; ++j) {
            const int idx = q + 4 * j;
            const v4f v = er[idx];
            s0 += v * wb4[0][idx];
            s1 += v * wb4[1][idx];
            s2 += v * wb4[2][idx];
        }
        float a0 = (s0.x + s0.y) + (s0.z + s0.w);
        float a1 = (s1.x + s1.y) + (s1.z + s1.w);
        float a2 = (s2.x + s2.y) + (s2.z + s2.w);
        a0 += __shfl_xor(a0, 1, 64); a0 += __shfl_xor(a0, 2, 64);
        a1 += __shfl_xor(a1, 1, 64); a1 += __shfl_xor(a1, 2, 64);
        a2 += __shfl_xor(a2, 1, 64); a2 += __shfl_xor(a2, 2, 64);

        if (q < NK) {
            const float val = (q == 0) ? a0 : (q == 1) ? a1 : a2;
            a_out[((size_t)c * NL + l) * NK + q] = val;
        }
    }
}

// ---------------------------------------------------------------------------
// Kernel B: R7 flattened b-stream store (measured: ~90 us incl. gap).
// ---------------------------------------------------------------------------
__global__ __launch_bounds__(256) void bstream_kernel(
    const float* __restrict__ a_in,   // [CFP4] float4
    const float* __restrict__ e_in,   // [B*C][K]
    float* __restrict__ out)          // [B][CFP4] float4
{
    const int bx = blockIdx.x;        // chunk 0..127
    const int b0 = blockIdx.y * GB;   // b-group start
    const int t  = threadIdx.x;

    __shared__ v4f e4[3][NC][GB];
    for (int i = t; i < 3 * NC * GB; i += 256) {
        const int p   = i / (NC * GB);
        const int rem = i - p * (NC * GB);
        const int c   = rem / GB;
        const int bl  = rem - c * GB;
        const float* ep = e_in + ((size_t)(b0 + bl) * NC + c) * NK;
        const float e0 = ep[0], e1 = ep[1], e2 = ep[2];
        v4f v;
        if      (p == 0) { v.x = e0; v.y = e1; v.z = e2; v.w = e0; }
        else if (p == 1) { v.x = e1; v.y = e2; v.z = e0; v.w = e1; }
        else             { v.x = e2; v.y = e0; v.z = e1; v.w = e2; }
        e4[p][c][bl] = v;
    }
    __syncthreads();

    const int base = bx * CHUNK;
    const v4f* a4 = reinterpret_cast<const v4f*>(a_in);

    v4f        av[NJ];
    const v4f* eptr[NJ];
    bool       gj[NJ];
    #pragma unroll
    for (int j = 0; j < NJ; ++j) {
        const int fo = j * 256 + t;
        const int f  = base + fo;
        gj[j] = (fo < CHUNK) && (f < CFP4);
        const int fc = gj[j] ? f : 0;
        eptr[j] = &e4[fc % 3][fc / FP4][0];
        av[j]   = gj[j] ? a4[fc] : (v4f)(0.f);
    }

    v4f* o4 = reinterpret_cast<v4f*>(out);
    size_t obase = (size_t)b0 * CFP4 + base;
    #pragma unroll 2
    for (int bl = 0; bl < GB; ++bl) {
        #pragma unroll
        for (int j = 0; j < NJ; ++j) {
            if (gj[j]) {
                const v4f ev = eptr[j][bl];
                v4f o;
                o.x = fmaxf(av[j].x + ev.x, 0.f);
                o.y = fmaxf(av[j].y + ev.y, 0.f);
                o.z = fmaxf(av[j].z + ev.z, 0.f);
                o.w = fmaxf(av[j].w + ev.w, 0.f);
                o4[obase + j * 256 + t] = o;
            }
        }
        obase += CFP4;
    }
}

// ---------------------------------------------------------------------------
// Fused fallback for the case ws_size is too small.
// ---------------------------------------------------------------------------
__global__ __launch_bounds__(256) void decoder_fused_kernel(
    const int*   __restrict__ bin_ids,
    const float* __restrict__ emb_table,
    const float* __restrict__ fc_W,
    const float* __restrict__ e_in,
    float* __restrict__ out)
{
    const int c   = blockIdx.y;
    const int tid = threadIdx.x;
    const int l   = blockIdx.x * 256 + tid;

    __shared__ float wb[NK][ND];
    __shared__ float es[NB * NK];

    if (tid < NK * ND)
        wb[tid / ND][tid % ND] = fc_W[(tid / ND) * (2 * ND) + (tid % ND)];
    if (tid < NB * NK) {
        int b = tid / NK, k = tid % NK;
        es[tid] = e_in[((size_t)b * NC + c) * NK + k];
    }
    __syncthreads();
    if (l >= NL) return;

    const int row = bin_ids[(size_t)c * NL + l];
    const float4* er = reinterpret_cast<const float4*>(emb_table + (size_t)row * ND);
    const float4* w0 = reinterpret_cast<const float4*>(wb[0]);
    const float4* w1 = reinterpret_cast<const float4*>(wb[1]);
    const float4* w2 = reinterpret_cast<const float4*>(wb[2]);

    float a0 = 0.f, a1 = 0.f, a2 = 0.f;
    #pragma unroll
    for (int i = 0; i < ND / 4; ++i) {
        float4 v  = er[i];
        float4 p0 = w0[i], p1 = w1[i], p2 = w2[i];
        a0 += v.x * p0.x + v.y * p0.y + v.z * p0.z + v.w * p0.w;
        a1 += v.x * p1.x + v.y * p1.y + v.z * p1.z + v.w * p1.w;
        a2 += v.x * p2.x + v.y * p2.y + v.z * p2.z + v.w * p2.w;
    }

    size_t obase = ((size_t)c * NL + l) * NK;
    const size_t bstride = (size_t)NC * NL * NK;
    #pragma unroll 4
    for (int b = 0; b < NB; ++b) {
        const float e0 = es[b * NK + 0];
        const float e1 = es[b * NK + 1];
        const float e2 = es[b * NK + 2];
        out[obase + 0] = fmaxf(a0 + e0, 0.f);
        out[obase + 1] = fmaxf(a1 + e1, 0.f);
        out[obase + 2] = fmaxf(a2 + e2, 0.f);
        obase += bstride;
    }
}

extern "C" void kernel_launch(void* const* d_in, const int* in_sizes, int n_in,
                              void* d_out, int out_size, void* d_ws, size_t ws_size,
                              hipStream_t stream) {
    const float* eos_emb   = (const float*)d_in[0];
    const int*   bin_ids   = (const int*)  d_in[1];
    const float* emb_table = (const float*)d_in[2];
    const float* eos_W     = (const float*)d_in[3];
    const float* eos_b     = (const float*)d_in[4];
    const float* fc_W      = (const float*)d_in[5];
    const float* fc_b      = (const float*)d_in[6];
    float*       out       = (float*)d_out;

    // ws layout: [0,32KB) e ; [32KB, +7.2MB) a ; [16MB ...) dummy e+a
    float*  e_ws = (float*)d_ws;
    const size_t a_off_bytes = 32768;
    float*  a_ws = (float*)((char*)d_ws + a_off_bytes);
    const size_t a_bytes = (size_t)NC * NL * NK * sizeof(float);

    const size_t dummy_off = 16ull * 1024 * 1024;
    float* e_dummy = (float*)((char*)d_ws + dummy_off);
    float* a_dummy = (float*)((char*)d_ws + dummy_off + a_off_bytes);

    if (ws_size >= a_off_bytes + a_bytes) {
        prep_kernel<<<NBC + ATOT, 256, 0, stream>>>(
            eos_emb, bin_ids, emb_table, eos_W, eos_b, fc_W, fc_b, e_ws, a_ws);

        dim3 grid_b(NCHUNK, NB / GB);               // 128 x 8 = 1024 blocks
        bstream_kernel<<<grid_b, 256, 0, stream>>>(a_ws, e_ws, out);

        // MEASUREMENT: identical second prep pass into ws scratch.
        // T_prep = (dur_us - 90.05 - gap) / 2
        if (ws_size >= dummy_off + a_off_bytes + a_bytes) {
            prep_kernel<<<NBC + ATOT, 256, 0, stream>>>(
                eos_emb, bin_ids, emb_table, eos_W, eos_b, fc_W, fc_b, e_dummy, a_dummy);
        }
    } else {
        // e-only prep then fused fallback
        prep_kernel<<<NBC, 256, 0, stream>>>(
            eos_emb, bin_ids, emb_table, eos_W, eos_b, fc_W, fc_b, e_ws, a_ws);
        dim3 grid((NL + 255) / 256, NC);
        decoder_fused_kernel<<<grid, 256, 0, stream>>>(bin_ids, emb_table, fc_W, e_ws, out);
    }
}

// Round 14
// 141.750 us; speedup vs baseline: 1.6695x; 1.2182x over previous
//
#include <hip/hip_runtime.h>

// Problem constants (from reference)
#define NB 64      // B
#define NC 23      // C
#define NL 26000   // L
#define ND 64      // D
#define NE 512     // E
#define NK 3       // K
#define FP4  (NL * NK / 4)          // 19500 float4 per (b,c) slice
#define CFP4 (NC * FP4)             // 448500 float4 per b slice
#define CHUNK 3504                  // float4 per block chunk (56 KB)
#define NCHUNK 128                  // 128 * 3504 = 448512 >= 448500
#define NJ 14                       // ceil(CHUNK / 256)
#define GB 8                        // b's per block (grid.y = 8)
#define NBC (NB * NC)               // 1472 eos units
#define ABLK 407                    // a-blocks per c (407*64 = 26048 >= 26000)
#define ATOT (ABLK * NC)            // 9361 a-blocks

typedef float v4f __attribute__((ext_vector_type(4)));

// ---------------------------------------------------------------------------
// Merged prep kernel: blocks [0, NBC) compute e[b,c,:]; blocks [NBC, NBC+ATOT)
// compute a[c,l,:].  Measured (R13 subtraction): ~41 us incl. launch gap.
// ---------------------------------------------------------------------------
__global__ __launch_bounds__(256) void prep_kernel(
    const float* __restrict__ eos_emb,   // [B][C][E]
    const int*   __restrict__ bin_ids,   // [C*L]
    const float* __restrict__ emb_table, // [V][D]
    const float* __restrict__ eos_W,     // [D][E]
    const float* __restrict__ eos_b,     // [D]
    const float* __restrict__ fc_W,      // [K][2D]
    const float* __restrict__ fc_b,      // [K]
    float* __restrict__ e_out,           // [B*C][K]
    float* __restrict__ a_out)           // [C][L][K]
{
    const int bx = blockIdx.x;
    const int t  = threadIdx.x;
    const int q  = t & 3;

    __shared__ v4f   xs4[NE / 4];        // eos path (2 KB)
    __shared__ float part[4][NK];
    __shared__ v4f   wb4[NK][ND / 4];    // a path (768 B)

    if (bx < NBC) {
        // ---------------- eos path ----------------
        const int bc = bx;
        const int d  = t >> 2;

        if (t < NE / 4)
            xs4[t] = reinterpret_cast<const v4f*>(eos_emb + (size_t)bc * NE)[t];
        __syncthreads();

        const v4f* wrow = reinterpret_cast<const v4f*>(eos_W + (size_t)d * NE);
        v4f acc = (v4f)(0.f);
        #pragma unroll 8
        for (int j = 0; j < NE / 16; ++j) {
            const int idx = q + 4 * j;
            acc += wrow[idx] * xs4[idx];
        }
        float p = (acc.x + acc.y) + (acc.z + acc.w);
        p += __shfl_xor(p, 1, 64);
        p += __shfl_xor(p, 2, 64);
        const float eosd = p + eos_b[d];

        #pragma unroll
        for (int k = 0; k < NK; ++k) {
            float pk = eosd * fc_W[k * (2 * ND) + ND + d];   // We[k][d]
            pk += __shfl_xor(pk,  4, 64);
            pk += __shfl_xor(pk,  8, 64);
            pk += __shfl_xor(pk, 16, 64);
            pk += __shfl_xor(pk, 32, 64);
            if ((t & 63) == 0) part[t >> 6][k] = pk;
        }
        __syncthreads();
        if (t < NK)
            e_out[(size_t)bc * NK + t] =
                part[0][t] + part[1][t] + part[2][t] + part[3][t] + fc_b[t];
    } else {
        // ---------------- a path ----------------
        const int ab = bx - NBC;        // 0..ATOT-1
        const int c  = ab / ABLK;
        const int lb = ab - c * ABLK;
        const int r  = t >> 2;
        const int l  = lb * 64 + r;

        if (t < NK * (ND / 4)) {
            const int k = t / (ND / 4), i = t % (ND / 4);
            wb4[k][i] = reinterpret_cast<const v4f*>(fc_W + (size_t)k * (2 * ND))[i];
        }
        __syncthreads();
        if (l >= NL) return;

        const int row = bin_ids[(size_t)c * NL + l];
        const v4f* er = reinterpret_cast<const v4f*>(emb_table + (size_t)row * ND);

        v4f s0 = (v4f)(0.f), s1 = (v4f)(0.f), s2 = (v4f)(0.f);
        #pragma unroll
        for (int j = 0; j < 4; ++j) {
            const int idx = q + 4 * j;
            const v4f v = er[idx];
            s0 += v * wb4[0][idx];
            s1 += v * wb4[1][idx];
            s2 += v * wb4[2][idx];
        }
        float a0 = (s0.x + s0.y) + (s0.z + s0.w);
        float a1 = (s1.x + s1.y) + (s1.z + s1.w);
        float a2 = (s2.x + s2.y) + (s2.z + s2.w);
        a0 += __shfl_xor(a0, 1, 64); a0 += __shfl_xor(a0, 2, 64);
        a1 += __shfl_xor(a1, 1, 64); a1 += __shfl_xor(a1, 2, 64);
        a2 += __shfl_xor(a2, 1, 64); a2 += __shfl_xor(a2, 2, 64);

        if (q < NK) {
            const float val = (q == 0) ? a0 : (q == 1) ? a1 : a2;
            a_out[((size_t)c * NL + l) * NK + q] = val;
        }
    }
}

// ---------------------------------------------------------------------------
// Kernel B: R7 flattened b-stream store (measured: ~90 us incl. gap).
// ---------------------------------------------------------------------------
__global__ __launch_bounds__(256) void bstream_kernel(
    const float* __restrict__ a_in,   // [CFP4] float4
    const float* __restrict__ e_in,   // [B*C][K]
    float* __restrict__ out)          // [B][CFP4] float4
{
    const int bx = blockIdx.x;        // chunk 0..127
    const int b0 = blockIdx.y * GB;   // b-group start
    const int t  = threadIdx.x;

    __shared__ v4f e4[3][NC][GB];
    for (int i = t; i < 3 * NC * GB; i += 256) {
        const int p   = i / (NC * GB);
        const int rem = i - p * (NC * GB);
        const int c   = rem / GB;
        const int bl  = rem - c * GB;
        const float* ep = e_in + ((size_t)(b0 + bl) * NC + c) * NK;
        const float e0 = ep[0], e1 = ep[1], e2 = ep[2];
        v4f v;
        if      (p == 0) { v.x = e0; v.y = e1; v.z = e2; v.w = e0; }
        else if (p == 1) { v.x = e1; v.y = e2; v.z = e0; v.w = e1; }
        else             { v.x = e2; v.y = e0; v.z = e1; v.w = e2; }
        e4[p][c][bl] = v;
    }
    __syncthreads();

    const int base = bx * CHUNK;
    const v4f* a4 = reinterpret_cast<const v4f*>(a_in);

    v4f        av[NJ];
    const v4f* eptr[NJ];
    bool       gj[NJ];
    #pragma unroll
    for (int j = 0; j < NJ; ++j) {
        const int fo = j * 256 + t;
        const int f  = base + fo;
        gj[j] = (fo < CHUNK) && (f < CFP4);
        const int fc = gj[j] ? f : 0;
        eptr[j] = &e4[fc % 3][fc / FP4][0];
        av[j]   = gj[j] ? a4[fc] : (v4f)(0.f);
    }

    v4f* o4 = reinterpret_cast<v4f*>(out);
    size_t obase = (size_t)b0 * CFP4 + base;
    #pragma unroll 2
    for (int bl = 0; bl < GB; ++bl) {
        #pragma unroll
        for (int j = 0; j < NJ; ++j) {
            if (gj[j]) {
                const v4f ev = eptr[j][bl];
                v4f o;
                o.x = fmaxf(av[j].x + ev.x, 0.f);
                o.y = fmaxf(av[j].y + ev.y, 0.f);
                o.z = fmaxf(av[j].z + ev.z, 0.f);
                o.w = fmaxf(av[j].w + ev.w, 0.f);
                o4[obase + j * 256 + t] = o;
            }
        }
        obase += CFP4;
    }
}

// ---------------------------------------------------------------------------
// Fused fallback for the case ws_size is too small.
// ---------------------------------------------------------------------------
__global__ __launch_bounds__(256) void decoder_fused_kernel(
    const int*   __restrict__ bin_ids,
    const float* __restrict__ emb_table,
    const float* __restrict__ fc_W,
    const float* __restrict__ e_in,
    float* __restrict__ out)
{
    const int c   = blockIdx.y;
    const int tid = threadIdx.x;
    const int l   = blockIdx.x * 256 + tid;

    __shared__ float wb[NK][ND];
    __shared__ float es[NB * NK];

    if (tid < NK * ND)
        wb[tid / ND][tid % ND] = fc_W[(tid / ND) * (2 * ND) + (tid % ND)];
    if (tid < NB * NK) {
        int b = tid / NK, k = tid % NK;
        es[tid] = e_in[((size_t)b * NC + c) * NK + k];
    }
    __syncthreads();
    if (l >= NL) return;

    const int row = bin_ids[(size_t)c * NL + l];
    const float4* er = reinterpret_cast<const float4*>(emb_table + (size_t)row * ND);
    const float4* w0 = reinterpret_cast<const float4*>(wb[0]);
    const float4* w1 = reinterpret_cast<const float4*>(wb[1]);
    const float4* w2 = reinterpret_cast<const float4*>(wb[2]);

    float a0 = 0.f, a1 = 0.f, a2 = 0.f;
    #pragma unroll
    for (int i = 0; i < ND / 4; ++i) {
        float4 v  = er[i];
        float4 p0 = w0[i], p1 = w1[i], p2 = w2[i];
        a0 += v.x * p0.x + v.y * p0.y + v.z * p0.z + v.w * p0.w;
        a1 += v.x * p1.x + v.y * p1.y + v.z * p1.z + v.w * p1.w;
        a2 += v.x * p2.x + v.y * p2.y + v.z * p2.z + v.w * p2.w;
    }

    size_t obase = ((size_t)c * NL + l) * NK;
    const size_t bstride = (size_t)NC * NL * NK;
    #pragma unroll 4
    for (int b = 0; b < NB; ++b) {
        const float e0 = es[b * NK + 0];
        const float e1 = es[b * NK + 1];
        const float e2 = es[b * NK + 2];
        out[obase + 0] = fmaxf(a0 + e0, 0.f);
        out[obase + 1] = fmaxf(a1 + e1, 0.f);
        out[obase + 2] = fmaxf(a2 + e2, 0.f);
        obase += bstride;
    }
}

extern "C" void kernel_launch(void* const* d_in, const int* in_sizes, int n_in,
                              void* d_out, int out_size, void* d_ws, size_t ws_size,
                              hipStream_t stream) {
    const float* eos_emb   = (const float*)d_in[0];
    const int*   bin_ids   = (const int*)  d_in[1];
    const float* emb_table = (const float*)d_in[2];
    const float* eos_W     = (const float*)d_in[3];
    const float* eos_b     = (const float*)d_in[4];
    const float* fc_W      = (const float*)d_in[5];
    const float* fc_b      = (const float*)d_in[6];
    float*       out       = (float*)d_out;

    // ws layout: [0,32KB) e ; [32KB, +7.2MB) a
    float*  e_ws = (float*)d_ws;
    const size_t a_off_bytes = 32768;
    float*  a_ws = (float*)((char*)d_ws + a_off_bytes);
    const size_t a_bytes = (size_t)NC * NL * NK * sizeof(float);

    if (ws_size >= a_off_bytes + a_bytes) {
        prep_kernel<<<NBC + ATOT, 256, 0, stream>>>(
            eos_emb, bin_ids, emb_table, eos_W, eos_b, fc_W, fc_b, e_ws, a_ws);

        dim3 grid_b(NCHUNK, NB / GB);               // 128 x 8 = 1024 blocks
        bstream_kernel<<<grid_b, 256, 0, stream>>>(a_ws, e_ws, out);
    } else {
        // e-only prep then fused fallback
        prep_kernel<<<NBC, 256, 0, stream>>>(
            eos_emb, bin_ids, emb_table, eos_W, eos_b, fc_W, fc_b, e_ws, a_ws);
        dim3 grid((NL + 255) / 256, NC);
        decoder_fused_kernel<<<grid, 256, 0, stream>>>(bin_ids, emb_table, fc_W, e_ws, out);
    }
}